// Round 6
// baseline (725.077 us; speedup 1.0000x reference)
//
#include <hip/hip_runtime.h>

// Per-point expert-indexed MLP: h = LeakyReLU(h @ W[idx] + b[idx]) x3.
//
// Pipeline (4 dispatches, all atomic-contention-free):
//   k_hist    : per-block histogram, partials stored expert-major [e][b]
//   k_scan    : 1 block x 1024 thr; wave w scans expert w's 1954 partials
//               (exclusive, in place) + publishes counts & padded offsets
//   k_scatter : deterministic position = soff[e] + prefix[e][b] + LDS rank;
//               stages sorted rows (7 floats + pid). NO global atomics
//               (R1-R5 used 16 global atomic cursors on ONE cache line).
//   k_mlp     : expert-uniform blocks; weights in LDS (4.8 KB, wave-broadcast
//               ds_read_b128); MPT=2 points/thread halves LDS-pipe demand
//               (R1's measured ~35us at MPT=1 -> ~20us); layers 1+2 FUSED so
//               live regs stay ~2x36/pt (R3/R4 lesson: unfused MPT=4 = 220
//               live VGPRs = 1 GB scratch spill).

#define L_EXP 16
#define IN0   7
#define C0    16
#define C1    32
#define C2    16
#define NEG   0.2f
#define BLK   256
#define MPT   2
#define SEGPAD (BLK * MPT)   // 512
#define NBM   2048           // max scatter/hist blocks (n <= 524288)

// ws layout (int32):
//   [0..15]          counts per expert   (k_scan)
//   [16..32]         padded seg offsets, [32] = padded total (k_scan)
//   [64 .. 64+16*NBM) partial hist -> exclusive block prefixes, expert-major
//   float idx 65536.. : staged rows, 8 floats/slot: x[0..6], as_float(pid)
#define WS_PART  64
#define WS_STAGE 65536

__global__ void k_hist(const int* __restrict__ idx, int n, int* __restrict__ ws) {
    __shared__ int bins[L_EXP];
    int t = threadIdx.x;
    if (t < L_EXP) bins[t] = 0;
    __syncthreads();
    int i = blockIdx.x * BLK + t;
    if (i < n) atomicAdd(&bins[idx[i] & 15], 1);
    __syncthreads();
    if (t < L_EXP) ws[WS_PART + t * NBM + blockIdx.x] = bins[t];
}

__global__ void k_scan(int* __restrict__ ws, int nblk) {
    int t = threadIdx.x;          // 1024 threads = 16 waves, wave w = expert w
    int e = t >> 6, l = t & 63;
    int running = 0;
    for (int c = 0; c < nblk; c += 64) {
        int b = c + l;
        int v = (b < nblk) ? ws[WS_PART + e * NBM + b] : 0;
        int s = v;                 // inclusive wave scan
#pragma unroll
        for (int d = 1; d < 64; d <<= 1) {
            int u = __shfl_up(s, d, 64);
            if (l >= d) s += u;
        }
        if (b < nblk) ws[WS_PART + e * NBM + b] = running + (s - v);  // exclusive
        running += __shfl(s, 63, 64);
    }
    if (l == 0) ws[e] = running;   // expert total
    __syncthreads();
    if (t == 0) {
        int run = 0;
        for (int q = 0; q < L_EXP; ++q) {
            ws[16 + q] = run;
            run += ((ws[q] + SEGPAD - 1) / SEGPAD) * SEGPAD;
        }
        ws[32] = run;
    }
}

__global__ void k_scatter(const int* __restrict__ idx, const float* __restrict__ x,
                          int n, const int* __restrict__ ws, float* __restrict__ stage) {
    __shared__ int soff[L_EXP];
    __shared__ int lcount[L_EXP];
    int t = threadIdx.x;
    if (t < L_EXP) { soff[t] = ws[16 + t]; lcount[t] = 0; }
    __syncthreads();
    int i = blockIdx.x * BLK + t;
    if (i < n) {
        int e = idx[i] & 15;
        int r = atomicAdd(&lcount[e], 1);                    // LDS only
        int pos = soff[e] + ws[WS_PART + e * NBM + blockIdx.x] + r;
        float xv[IN0];
#pragma unroll
        for (int c = 0; c < IN0; ++c) xv[c] = x[i * IN0 + c];
        float4* sp = reinterpret_cast<float4*>(stage + (size_t)pos * 8);
        sp[0] = make_float4(xv[0], xv[1], xv[2], xv[3]);
        sp[1] = make_float4(xv[4], xv[5], xv[6], __int_as_float(i));
    }
}

__device__ __forceinline__ float leaky(float a) { return fmaxf(a, NEG * a); }

__device__ __forceinline__ float4 f4_fma(float s, float4 w, float4 a) {
    a.x = fmaf(s, w.x, a.x);
    a.y = fmaf(s, w.y, a.y);
    a.z = fmaf(s, w.z, a.z);
    a.w = fmaf(s, w.w, a.w);
    return a;
}

__global__ void __launch_bounds__(BLK) k_mlp(
    const int* __restrict__ meta, const float* __restrict__ stage,
    const float* __restrict__ W0, const float* __restrict__ b0,
    const float* __restrict__ W1, const float* __restrict__ b1,
    const float* __restrict__ W2, const float* __restrict__ b2,
    float* __restrict__ out) {
    __shared__ __align__(16) float sW0[IN0 * C0];
    __shared__ __align__(16) float sB0[C0];
    __shared__ __align__(16) float sW1[C0 * C1];
    __shared__ __align__(16) float sB1[C1];
    __shared__ __align__(16) float sW2[C1 * C2];
    __shared__ __align__(16) float sB2[C2];

    int start = blockIdx.x * SEGPAD;
    if (start >= meta[32]) return;  // uniform

    int e = 0;
    while (start >= meta[16 + e + 1]) ++e;
    e = __builtin_amdgcn_readfirstlane(e);

    int t = threadIdx.x;
    {
        const float* w0p = W0 + e * (IN0 * C0);
        const float* w1p = W1 + e * (C0 * C1);
        const float* w2p = W2 + e * (C1 * C2);
        if (t < IN0 * C0) sW0[t] = w0p[t];
        if (t >= 128 && t < 128 + C0) sB0[t - 128] = b0[e * C0 + (t - 128)];
        if (t >= 160 && t < 160 + C1) sB1[t - 160] = b1[e * C1 + (t - 160)];
        if (t >= 192 && t < 192 + C2) sB2[t - 192] = b2[e * C2 + (t - 192)];
        for (int k = t; k < C0 * C1; k += BLK) sW1[k] = w1p[k];
        for (int k = t; k < C1 * C2; k += BLK) sW2[k] = w2p[k];
    }
    __syncthreads();

    int seg = meta[16 + e];
    int cnt = meta[e];
    int j0 = start - seg + t;

    float xv[MPT][IN0];
    int   pid[MPT];
    bool  act[MPT];
#pragma unroll
    for (int m = 0; m < MPT; ++m) {
        int j = j0 + m * BLK;
        act[m] = (j < cnt);
        // pad slots hold 0xAA poison = valid finite floats; stores are predicated
        const float4* sp = reinterpret_cast<const float4*>(stage + (size_t)(seg + j) * 8);
        float4 a = sp[0];
        float4 b = sp[1];
        xv[m][0] = a.x; xv[m][1] = a.y; xv[m][2] = a.z; xv[m][3] = a.w;
        xv[m][4] = b.x; xv[m][5] = b.y; xv[m][6] = b.z;
        pid[m] = __float_as_int(b.w);
    }

    // ---- Layer 0: 7 -> 16 ----
    float h0[MPT][C0];
#pragma unroll
    for (int og = 0; og < C0 / 4; ++og) {
        float4 bb = *reinterpret_cast<const float4*>(&sB0[og * 4]);
        float4 acc[MPT];
#pragma unroll
        for (int m = 0; m < MPT; ++m) acc[m] = bb;
#pragma unroll
        for (int c = 0; c < IN0; ++c) {
            float4 w = *reinterpret_cast<const float4*>(&sW0[c * C0 + og * 4]);
#pragma unroll
            for (int m = 0; m < MPT; ++m) acc[m] = f4_fma(xv[m][c], w, acc[m]);
        }
#pragma unroll
        for (int m = 0; m < MPT; ++m) {
            h0[m][og * 4 + 0] = leaky(acc[m].x);
            h0[m][og * 4 + 1] = leaky(acc[m].y);
            h0[m][og * 4 + 2] = leaky(acc[m].z);
            h0[m][og * 4 + 3] = leaky(acc[m].w);
        }
    }

    // ---- Layers 1+2 fused: h1 in chunks of 4, accumulate into h2 ----
    // live/point: h0[16] + h2[16] + chunk[4] = 36 regs -> ~110-130 total @MPT=2
    float4 h2[MPT][C2 / 4];
#pragma unroll
    for (int og = 0; og < C2 / 4; ++og) {
        float4 bb = *reinterpret_cast<const float4*>(&sB2[og * 4]);
#pragma unroll
        for (int m = 0; m < MPT; ++m) h2[m][og] = bb;
    }
#pragma unroll
    for (int ch = 0; ch < C1 / 4; ++ch) {
        float4 tv[MPT];
        float4 bb = *reinterpret_cast<const float4*>(&sB1[ch * 4]);
#pragma unroll
        for (int m = 0; m < MPT; ++m) tv[m] = bb;
#pragma unroll
        for (int c = 0; c < C0; ++c) {
            float4 w = *reinterpret_cast<const float4*>(&sW1[c * C1 + ch * 4]);
#pragma unroll
            for (int m = 0; m < MPT; ++m) tv[m] = f4_fma(h0[m][c], w, tv[m]);
        }
#pragma unroll
        for (int m = 0; m < MPT; ++m) {
            tv[m].x = leaky(tv[m].x); tv[m].y = leaky(tv[m].y);
            tv[m].z = leaky(tv[m].z); tv[m].w = leaky(tv[m].w);
        }
#pragma unroll
        for (int q = 0; q < 4; ++q) {
            int c1 = ch * 4 + q;
#pragma unroll
            for (int og = 0; og < C2 / 4; ++og) {
                float4 w = *reinterpret_cast<const float4*>(&sW2[c1 * C2 + og * 4]);
#pragma unroll
                for (int m = 0; m < MPT; ++m) {
                    float s = (q == 0) ? tv[m].x : (q == 1) ? tv[m].y
                                       : (q == 2) ? tv[m].z : tv[m].w;
                    h2[m][og] = f4_fma(s, w, h2[m][og]);
                }
            }
        }
    }

    // ---- predicated stores ----
#pragma unroll
    for (int m = 0; m < MPT; ++m) {
        if (act[m]) {
            float4* outp = reinterpret_cast<float4*>(out + (size_t)pid[m] * C2);
#pragma unroll
            for (int og = 0; og < C2 / 4; ++og) {
                float4 o = h2[m][og];
                o.x = leaky(o.x); o.y = leaky(o.y);
                o.z = leaky(o.z); o.w = leaky(o.w);
                outp[og] = o;
            }
        }
    }
}

extern "C" void kernel_launch(void* const* d_in, const int* in_sizes, int n_in,
                              void* d_out, int out_size, void* d_ws, size_t ws_size,
                              hipStream_t stream) {
    const float* x  = (const float*)d_in[0];
    const int*  idx = (const int*)d_in[1];
    const float* W0 = (const float*)d_in[2];
    const float* b0 = (const float*)d_in[3];
    const float* W1 = (const float*)d_in[4];
    const float* b1 = (const float*)d_in[5];
    const float* W2 = (const float*)d_in[6];
    const float* b2 = (const float*)d_in[7];
    float* out = (float*)d_out;

    int n = in_sizes[1];  // N
    int* ws = (int*)d_ws;
    float* stage = (float*)d_ws + WS_STAGE;

    int nblk = (n + BLK - 1) / BLK;   // <= NBM
    k_hist<<<nblk, BLK, 0, stream>>>(idx, n, ws);
    k_scan<<<1, 1024, 0, stream>>>(ws, nblk);
    k_scatter<<<nblk, BLK, 0, stream>>>(idx, x, n, ws, stage);

    int mblk = (n + L_EXP * (SEGPAD - 1) + SEGPAD - 1) / SEGPAD;
    k_mlp<<<mblk, BLK, 0, stream>>>(ws, stage, W0, b0, W1, b1, W2, b2, out);
}

// Round 7
// 134.117 us; speedup vs baseline: 5.4063x; 5.4063x over previous
//
#include <hip/hip_runtime.h>

// Per-point expert-indexed MLP: h = LeakyReLU(h @ W[idx] + b[idx]) x3.
//
// Pipeline (4 dispatches):
//   k_hist    : per-block histogram, partials expert-major [e][b]
//   k_scan    : 1 block x 1024; wave e scans expert e's partials (exclusive)
//   k_scatter : deterministic pos = soff[e] + prefix[e][b] + LDS rank; stages
//               sorted rows (7 floats + pid). No global atomics.
//   k_mlp     : expert-uniform blocks, weights in LDS (4.8 KB, broadcast),
//               MPT=2 points/thread.
//
// R6 LESSON (the spill root cause): in a fully-unrolled MPT>=2 body the
// pre-RA scheduler hoists ALL ~568 ds_read_b128 weight loads above their FMA
// consumers, exploding live ranges past 256 VGPRs -> GB-scale scratch spill.
// Containment here: (1) the fused L1+L2 chunk loop is a REAL loop
// (#pragma unroll 1) so loads can't be hoisted across the back-edge; (2)
// sched_barrier(0) fences between phases; (3) __launch_bounds__(256,3) caps
// allocation (~168 VGPR). Static live set at MPT=2 fused is only ~85 floats.

#define L_EXP 16
#define IN0   7
#define C0    16
#define C1    32
#define C2    16
#define NEG   0.2f
#define BLK   256
#define MPT   2
#define SEGPAD (BLK * MPT)   // 512
#define NBM   2048           // max hist/scatter blocks (n <= 524288)

// ws layout (int32):
//   [0..15]           counts per expert   (k_scan)
//   [16..32]          padded seg offsets, [32] = padded total (k_scan)
//   [64 .. 64+16*NBM) partial hist -> exclusive block prefixes, expert-major
//   float idx 65536.. : staged rows, 8 floats/slot: x[0..6], as_float(pid)
#define WS_PART  64
#define WS_STAGE 65536

__global__ void k_hist(const int* __restrict__ idx, int n, int* __restrict__ ws) {
    __shared__ int bins[L_EXP];
    int t = threadIdx.x;
    if (t < L_EXP) bins[t] = 0;
    __syncthreads();
    int i = blockIdx.x * BLK + t;
    if (i < n) atomicAdd(&bins[idx[i] & 15], 1);
    __syncthreads();
    if (t < L_EXP) ws[WS_PART + t * NBM + blockIdx.x] = bins[t];
}

__global__ void k_scan(int* __restrict__ ws, int nblk) {
    int t = threadIdx.x;          // 1024 threads = 16 waves, wave e = expert e
    int e = t >> 6, l = t & 63;
    int running = 0;
    for (int c = 0; c < nblk; c += 64) {
        int b = c + l;
        int v = (b < nblk) ? ws[WS_PART + e * NBM + b] : 0;
        int s = v;                 // inclusive wave scan
#pragma unroll
        for (int d = 1; d < 64; d <<= 1) {
            int u = __shfl_up(s, d, 64);
            if (l >= d) s += u;
        }
        if (b < nblk) ws[WS_PART + e * NBM + b] = running + (s - v);  // exclusive
        running += __shfl(s, 63, 64);
    }
    if (l == 0) ws[e] = running;   // expert total
    __syncthreads();
    if (t == 0) {
        int run = 0;
        for (int q = 0; q < L_EXP; ++q) {
            ws[16 + q] = run;
            run += ((ws[q] + SEGPAD - 1) / SEGPAD) * SEGPAD;
        }
        ws[32] = run;
    }
}

__global__ void k_scatter(const int* __restrict__ idx, const float* __restrict__ x,
                          int n, const int* __restrict__ ws, float* __restrict__ stage) {
    __shared__ int soff[L_EXP];
    __shared__ int lcount[L_EXP];
    int t = threadIdx.x;
    if (t < L_EXP) { soff[t] = ws[16 + t]; lcount[t] = 0; }
    __syncthreads();
    int i = blockIdx.x * BLK + t;
    if (i < n) {
        int e = idx[i] & 15;
        int r = atomicAdd(&lcount[e], 1);                    // LDS only
        int pos = soff[e] + ws[WS_PART + e * NBM + blockIdx.x] + r;
        float xv[IN0];
#pragma unroll
        for (int c = 0; c < IN0; ++c) xv[c] = x[i * IN0 + c];
        float4* sp = reinterpret_cast<float4*>(stage + (size_t)pos * 8);
        sp[0] = make_float4(xv[0], xv[1], xv[2], xv[3]);
        sp[1] = make_float4(xv[4], xv[5], xv[6], __int_as_float(i));
    }
}

__device__ __forceinline__ float leaky(float a) { return fmaxf(a, NEG * a); }

__device__ __forceinline__ float4 f4_fma(float s, float4 w, float4 a) {
    a.x = fmaf(s, w.x, a.x);
    a.y = fmaf(s, w.y, a.y);
    a.z = fmaf(s, w.z, a.z);
    a.w = fmaf(s, w.w, a.w);
    return a;
}

__global__ void __launch_bounds__(BLK, 3) k_mlp(
    const int* __restrict__ meta, const float* __restrict__ stage,
    const float* __restrict__ W0, const float* __restrict__ b0,
    const float* __restrict__ W1, const float* __restrict__ b1,
    const float* __restrict__ W2, const float* __restrict__ b2,
    float* __restrict__ out) {
    __shared__ __align__(16) float sW0[IN0 * C0];
    __shared__ __align__(16) float sB0[C0];
    __shared__ __align__(16) float sW1[C0 * C1];
    __shared__ __align__(16) float sB1[C1];
    __shared__ __align__(16) float sW2[C1 * C2];
    __shared__ __align__(16) float sB2[C2];

    int start = blockIdx.x * SEGPAD;
    if (start >= meta[32]) return;  // uniform

    int e = 0;
    while (start >= meta[16 + e + 1]) ++e;
    e = __builtin_amdgcn_readfirstlane(e);

    int t = threadIdx.x;
    {
        const float* w0p = W0 + e * (IN0 * C0);
        const float* w1p = W1 + e * (C0 * C1);
        const float* w2p = W2 + e * (C1 * C2);
        if (t < IN0 * C0) sW0[t] = w0p[t];
        if (t >= 128 && t < 128 + C0) sB0[t - 128] = b0[e * C0 + (t - 128)];
        if (t >= 160 && t < 160 + C1) sB1[t - 160] = b1[e * C1 + (t - 160)];
        if (t >= 192 && t < 192 + C2) sB2[t - 192] = b2[e * C2 + (t - 192)];
        for (int k = t; k < C0 * C1; k += BLK) sW1[k] = w1p[k];
        for (int k = t; k < C1 * C2; k += BLK) sW2[k] = w2p[k];
    }
    __syncthreads();

    int seg = meta[16 + e];
    int cnt = meta[e];
    int j0 = start - seg + t;

    float xv[MPT][IN0];
    int   pid[MPT];
    bool  act[MPT];
#pragma unroll
    for (int m = 0; m < MPT; ++m) {
        int j = j0 + m * BLK;
        act[m] = (j < cnt);
        // pad slots hold 0xAA poison = valid finite floats; stores predicated
        const float4* sp = reinterpret_cast<const float4*>(stage + (size_t)(seg + j) * 8);
        float4 a = sp[0];
        float4 b = sp[1];
        xv[m][0] = a.x; xv[m][1] = a.y; xv[m][2] = a.z; xv[m][3] = a.w;
        xv[m][4] = b.x; xv[m][5] = b.y; xv[m][6] = b.z;
        pid[m] = __float_as_int(b.w);
    }
    __builtin_amdgcn_sched_barrier(0);  // fence: don't hoist weight loads above

    // ---- Layer 0: 7 -> 16 ----
    float h0[MPT][C0];
#pragma unroll
    for (int og = 0; og < C0 / 4; ++og) {
        float4 bb = *reinterpret_cast<const float4*>(&sB0[og * 4]);
        float4 acc[MPT];
#pragma unroll
        for (int m = 0; m < MPT; ++m) acc[m] = bb;
#pragma unroll
        for (int c = 0; c < IN0; ++c) {
            float4 w = *reinterpret_cast<const float4*>(&sW0[c * C0 + og * 4]);
#pragma unroll
            for (int m = 0; m < MPT; ++m) acc[m] = f4_fma(xv[m][c], w, acc[m]);
        }
#pragma unroll
        for (int m = 0; m < MPT; ++m) {
            h0[m][og * 4 + 0] = leaky(acc[m].x);
            h0[m][og * 4 + 1] = leaky(acc[m].y);
            h0[m][og * 4 + 2] = leaky(acc[m].z);
            h0[m][og * 4 + 3] = leaky(acc[m].w);
        }
    }
    __builtin_amdgcn_sched_barrier(0);  // fence between layer 0 and fused 1+2

    // ---- Layers 1+2 fused; REAL loop (unroll 1) bounds in-flight loads ----
    float4 h2[MPT][C2 / 4];
#pragma unroll
    for (int og = 0; og < C2 / 4; ++og) {
        float4 bb = *reinterpret_cast<const float4*>(&sB2[og * 4]);
#pragma unroll
        for (int m = 0; m < MPT; ++m) h2[m][og] = bb;
    }
#pragma unroll 1
    for (int ch = 0; ch < C1 / 4; ++ch) {   // h1 neurons ch*4 .. ch*4+3
        float4 tv[MPT];
        float4 bb = *reinterpret_cast<const float4*>(&sB1[ch * 4]);
#pragma unroll
        for (int m = 0; m < MPT; ++m) tv[m] = bb;
#pragma unroll
        for (int c = 0; c < C0; ++c) {
            float4 w = *reinterpret_cast<const float4*>(&sW1[c * C1 + ch * 4]);
#pragma unroll
            for (int m = 0; m < MPT; ++m) tv[m] = f4_fma(h0[m][c], w, tv[m]);
        }
#pragma unroll
        for (int m = 0; m < MPT; ++m) {
            tv[m].x = leaky(tv[m].x); tv[m].y = leaky(tv[m].y);
            tv[m].z = leaky(tv[m].z); tv[m].w = leaky(tv[m].w);
        }
#pragma unroll
        for (int q = 0; q < 4; ++q) {
#pragma unroll
            for (int og = 0; og < C2 / 4; ++og) {
                float4 w = *reinterpret_cast<const float4*>(&sW2[(ch * 4 + q) * C2 + og * 4]);
#pragma unroll
                for (int m = 0; m < MPT; ++m) {
                    float s = (q == 0) ? tv[m].x : (q == 1) ? tv[m].y
                                       : (q == 2) ? tv[m].z : tv[m].w;
                    h2[m][og] = f4_fma(s, w, h2[m][og]);
                }
            }
        }
        __builtin_amdgcn_sched_barrier(0);  // fence at chunk boundary
    }

    // ---- predicated stores ----
#pragma unroll
    for (int m = 0; m < MPT; ++m) {
        if (act[m]) {
            float4* outp = reinterpret_cast<float4*>(out + (size_t)pid[m] * C2);
#pragma unroll
            for (int og = 0; og < C2 / 4; ++og) {
                float4 o = h2[m][og];
                o.x = leaky(o.x); o.y = leaky(o.y);
                o.z = leaky(o.z); o.w = leaky(o.w);
                outp[og] = o;
            }
        }
    }
}

extern "C" void kernel_launch(void* const* d_in, const int* in_sizes, int n_in,
                              void* d_out, int out_size, void* d_ws, size_t ws_size,
                              hipStream_t stream) {
    const float* x  = (const float*)d_in[0];
    const int*  idx = (const int*)d_in[1];
    const float* W0 = (const float*)d_in[2];
    const float* b0 = (const float*)d_in[3];
    const float* W1 = (const float*)d_in[4];
    const float* b1 = (const float*)d_in[5];
    const float* W2 = (const float*)d_in[6];
    const float* b2 = (const float*)d_in[7];
    float* out = (float*)d_out;

    int n = in_sizes[1];  // N
    int* ws = (int*)d_ws;
    float* stage = (float*)d_ws + WS_STAGE;

    int nblk = (n + BLK - 1) / BLK;   // <= NBM
    k_hist<<<nblk, BLK, 0, stream>>>(idx, n, ws);
    k_scan<<<1, 1024, 0, stream>>>(ws, nblk);
    k_scatter<<<nblk, BLK, 0, stream>>>(idx, x, n, ws, stage);

    int mblk = (n + L_EXP * (SEGPAD - 1) + SEGPAD - 1) / SEGPAD;
    k_mlp<<<mblk, BLK, 0, stream>>>(ws, stage, W0, b0, W1, b1, W2, b2, out);
}

// Round 8
// 120.943 us; speedup vs baseline: 5.9952x; 1.1089x over previous
//
#include <hip/hip_runtime.h>

// Per-point expert-indexed MLP: h = LeakyReLU(h @ W[idx] + b[idx]) x3.
//
// Pipeline (4 dispatches):
//   k_hist    : 1024 pts/block histogram, partials expert-major [e][b]
//   k_scan    : 1 block x 1024; wave e scans expert e's <=512 partials
//   k_scatter : deterministic pos = soff[e] + prefix[e][b] + LDS rank; stages
//               sorted rows (7 floats + pid). No global atomics.
//   k_mlp     : expert-uniform blocks, weights in LDS (4.8 KB, broadcast),
//               MPT=4 points/thread.
//
// VERIFIED MODEL (R7): k_mlp is LDS-pipe bound: ~300 ds_read_b128/thread
// x 12 cyc; MPT=2 measured 23us == model. MPT=4 halves reads/point -> ~11.5us.
// SPILL CONTAINMENT (R6 lesson: pre-RA scheduler hoists all weight loads in
// straight-line code -> 256 VGPR + GB-scale scratch): layer 0 split into two
// sched_barrier-fenced halves (<=16 loads in flight); fused L1+L2 is a REAL
// loop (#pragma unroll 1, loads can't cross the back-edge); launch_bounds
// (256,2) caps at 256 VGPR. Static live at MPT=4 ~190.

#define L_EXP 16
#define IN0   7
#define C0    16
#define C1    32
#define C2    16
#define NEG   0.2f
#define BLK   256
#define MPT   4
#define SEGPAD (BLK * MPT)   // 1024
#define CHUNK  1024          // points per hist/scatter block
#define NBM    512           // max hist/scatter blocks (n <= 524288)

// ws layout (int32):
//   [0..15]           counts per expert   (k_scan)
//   [16..32]          padded seg offsets, [32] = padded total (k_scan)
//   [64 .. 64+16*NBM) partial hist -> exclusive block prefixes, expert-major
//   float idx 16384.. : staged rows, 8 floats/slot: x[0..6], as_float(pid)
#define WS_PART  64
#define WS_STAGE 16384

__global__ void k_hist(const int* __restrict__ idx, int n, int* __restrict__ ws) {
    __shared__ int bins[L_EXP];
    int t = threadIdx.x;
    if (t < L_EXP) bins[t] = 0;
    __syncthreads();
#pragma unroll
    for (int s = 0; s < CHUNK / BLK; ++s) {
        int i = blockIdx.x * CHUNK + s * BLK + t;
        if (i < n) atomicAdd(&bins[idx[i] & 15], 1);
    }
    __syncthreads();
    if (t < L_EXP) ws[WS_PART + t * NBM + blockIdx.x] = bins[t];
}

__global__ void k_scan(int* __restrict__ ws, int nblk) {
    int t = threadIdx.x;          // 1024 threads = 16 waves, wave e = expert e
    int e = t >> 6, l = t & 63;
    int running = 0;
    for (int c = 0; c < nblk; c += 64) {
        int b = c + l;
        int v = (b < nblk) ? ws[WS_PART + e * NBM + b] : 0;
        int s = v;                 // inclusive wave scan
#pragma unroll
        for (int d = 1; d < 64; d <<= 1) {
            int u = __shfl_up(s, d, 64);
            if (l >= d) s += u;
        }
        if (b < nblk) ws[WS_PART + e * NBM + b] = running + (s - v);  // exclusive
        running += __shfl(s, 63, 64);
    }
    if (l == 0) ws[e] = running;   // expert total
    __syncthreads();
    if (t == 0) {
        int run = 0;
        for (int q = 0; q < L_EXP; ++q) {
            ws[16 + q] = run;
            run += ((ws[q] + SEGPAD - 1) / SEGPAD) * SEGPAD;
        }
        ws[32] = run;
    }
}

__global__ void k_scatter(const int* __restrict__ idx, const float* __restrict__ x,
                          int n, const int* __restrict__ ws, float* __restrict__ stage) {
    __shared__ int soff[L_EXP];   // seg offset + block prefix, combined
    __shared__ int lcount[L_EXP];
    int t = threadIdx.x;
    if (t < L_EXP) {
        soff[t] = ws[16 + t] + ws[WS_PART + t * NBM + blockIdx.x];
        lcount[t] = 0;
    }
    __syncthreads();
#pragma unroll
    for (int s = 0; s < CHUNK / BLK; ++s) {
        int i = blockIdx.x * CHUNK + s * BLK + t;
        if (i < n) {
            int e = idx[i] & 15;
            int r = atomicAdd(&lcount[e], 1);                // LDS only
            int pos = soff[e] + r;
            float xv[IN0];
#pragma unroll
            for (int c = 0; c < IN0; ++c) xv[c] = x[i * IN0 + c];
            float4* sp = reinterpret_cast<float4*>(stage + (size_t)pos * 8);
            sp[0] = make_float4(xv[0], xv[1], xv[2], xv[3]);
            sp[1] = make_float4(xv[4], xv[5], xv[6], __int_as_float(i));
        }
    }
}

__device__ __forceinline__ float leaky(float a) { return fmaxf(a, NEG * a); }

__device__ __forceinline__ float4 f4_fma(float s, float4 w, float4 a) {
    a.x = fmaf(s, w.x, a.x);
    a.y = fmaf(s, w.y, a.y);
    a.z = fmaf(s, w.z, a.z);
    a.w = fmaf(s, w.w, a.w);
    return a;
}

__global__ void __launch_bounds__(BLK, 2) k_mlp(
    const int* __restrict__ meta, const float* __restrict__ stage,
    const float* __restrict__ W0, const float* __restrict__ b0,
    const float* __restrict__ W1, const float* __restrict__ b1,
    const float* __restrict__ W2, const float* __restrict__ b2,
    float* __restrict__ out) {
    __shared__ __align__(16) float sW0[IN0 * C0];
    __shared__ __align__(16) float sB0[C0];
    __shared__ __align__(16) float sW1[C0 * C1];
    __shared__ __align__(16) float sB1[C1];
    __shared__ __align__(16) float sW2[C1 * C2];
    __shared__ __align__(16) float sB2[C2];

    int start = blockIdx.x * SEGPAD;
    if (start >= meta[32]) return;  // uniform

    int e = 0;
    while (start >= meta[16 + e + 1]) ++e;
    e = __builtin_amdgcn_readfirstlane(e);

    int t = threadIdx.x;
    {
        const float* w0p = W0 + e * (IN0 * C0);
        const float* w1p = W1 + e * (C0 * C1);
        const float* w2p = W2 + e * (C1 * C2);
        if (t < IN0 * C0) sW0[t] = w0p[t];
        if (t >= 128 && t < 128 + C0) sB0[t - 128] = b0[e * C0 + (t - 128)];
        if (t >= 160 && t < 160 + C1) sB1[t - 160] = b1[e * C1 + (t - 160)];
        if (t >= 192 && t < 192 + C2) sB2[t - 192] = b2[e * C2 + (t - 192)];
        for (int k = t; k < C0 * C1; k += BLK) sW1[k] = w1p[k];
        for (int k = t; k < C1 * C2; k += BLK) sW2[k] = w2p[k];
    }
    __syncthreads();

    int seg = meta[16 + e];
    int cnt = meta[e];
    int j0 = start - seg + t;

    float xv[MPT][IN0];
    int   pid[MPT];
    bool  act[MPT];
#pragma unroll
    for (int m = 0; m < MPT; ++m) {
        int j = j0 + m * BLK;
        act[m] = (j < cnt);
        // pad slots hold 0xAA poison = valid finite floats; stores predicated
        const float4* sp = reinterpret_cast<const float4*>(stage + (size_t)(seg + j) * 8);
        float4 a = sp[0];
        float4 b = sp[1];
        xv[m][0] = a.x; xv[m][1] = a.y; xv[m][2] = a.z; xv[m][3] = a.w;
        xv[m][4] = b.x; xv[m][5] = b.y; xv[m][6] = b.z;
        pid[m] = __float_as_int(b.w);
    }
    __builtin_amdgcn_sched_barrier(0);

    // ---- Layer 0: 7 -> 16, two fenced halves (<=16 b128 in flight each) ----
    float h0[MPT][C0];
#pragma unroll
    for (int og = 0; og < C0 / 4; ++og) {
        float4 bb = *reinterpret_cast<const float4*>(&sB0[og * 4]);
        float4 acc[MPT];
#pragma unroll
        for (int m = 0; m < MPT; ++m) acc[m] = bb;
#pragma unroll
        for (int c = 0; c < IN0; ++c) {
            float4 w = *reinterpret_cast<const float4*>(&sW0[c * C0 + og * 4]);
#pragma unroll
            for (int m = 0; m < MPT; ++m) acc[m] = f4_fma(xv[m][c], w, acc[m]);
        }
#pragma unroll
        for (int m = 0; m < MPT; ++m) {
            h0[m][og * 4 + 0] = leaky(acc[m].x);
            h0[m][og * 4 + 1] = leaky(acc[m].y);
            h0[m][og * 4 + 2] = leaky(acc[m].z);
            h0[m][og * 4 + 3] = leaky(acc[m].w);
        }
        if (og == 1) __builtin_amdgcn_sched_barrier(0);  // mid-layer fence
    }
    __builtin_amdgcn_sched_barrier(0);

    // ---- Layers 1+2 fused; REAL loop (unroll 1) bounds in-flight loads ----
    float4 h2[MPT][C2 / 4];
#pragma unroll
    for (int og = 0; og < C2 / 4; ++og) {
        float4 bb = *reinterpret_cast<const float4*>(&sB2[og * 4]);
#pragma unroll
        for (int m = 0; m < MPT; ++m) h2[m][og] = bb;
    }
#pragma unroll 1
    for (int ch = 0; ch < C1 / 4; ++ch) {   // h1 neurons ch*4 .. ch*4+3
        float4 tv[MPT];
        float4 bb = *reinterpret_cast<const float4*>(&sB1[ch * 4]);
#pragma unroll
        for (int m = 0; m < MPT; ++m) tv[m] = bb;
#pragma unroll
        for (int c = 0; c < C0; ++c) {
            float4 w = *reinterpret_cast<const float4*>(&sW1[c * C1 + ch * 4]);
#pragma unroll
            for (int m = 0; m < MPT; ++m) tv[m] = f4_fma(h0[m][c], w, tv[m]);
        }
#pragma unroll
        for (int m = 0; m < MPT; ++m) {
            tv[m].x = leaky(tv[m].x); tv[m].y = leaky(tv[m].y);
            tv[m].z = leaky(tv[m].z); tv[m].w = leaky(tv[m].w);
        }
#pragma unroll
        for (int q = 0; q < 4; ++q) {
#pragma unroll
            for (int og = 0; og < C2 / 4; ++og) {
                float4 w = *reinterpret_cast<const float4*>(&sW2[(ch * 4 + q) * C2 + og * 4]);
#pragma unroll
                for (int m = 0; m < MPT; ++m) {
                    float s = (q == 0) ? tv[m].x : (q == 1) ? tv[m].y
                                       : (q == 2) ? tv[m].z : tv[m].w;
                    h2[m][og] = f4_fma(s, w, h2[m][og]);
                }
            }
        }
        __builtin_amdgcn_sched_barrier(0);  // fence at chunk boundary
    }

    // ---- predicated stores ----
#pragma unroll
    for (int m = 0; m < MPT; ++m) {
        if (act[m]) {
            float4* outp = reinterpret_cast<float4*>(out + (size_t)pid[m] * C2);
#pragma unroll
            for (int og = 0; og < C2 / 4; ++og) {
                float4 o = h2[m][og];
                o.x = leaky(o.x); o.y = leaky(o.y);
                o.z = leaky(o.z); o.w = leaky(o.w);
                outp[og] = o;
            }
        }
    }
}

extern "C" void kernel_launch(void* const* d_in, const int* in_sizes, int n_in,
                              void* d_out, int out_size, void* d_ws, size_t ws_size,
                              hipStream_t stream) {
    const float* x  = (const float*)d_in[0];
    const int*  idx = (const int*)d_in[1];
    const float* W0 = (const float*)d_in[2];
    const float* b0 = (const float*)d_in[3];
    const float* W1 = (const float*)d_in[4];
    const float* b1 = (const float*)d_in[5];
    const float* W2 = (const float*)d_in[6];
    const float* b2 = (const float*)d_in[7];
    float* out = (float*)d_out;

    int n = in_sizes[1];  // N
    int* ws = (int*)d_ws;
    float* stage = (float*)d_ws + WS_STAGE;

    int nblk = (n + CHUNK - 1) / CHUNK;   // <= NBM
    k_hist<<<nblk, BLK, 0, stream>>>(idx, n, ws);
    k_scan<<<1, 1024, 0, stream>>>(ws, nblk);
    k_scatter<<<nblk, BLK, 0, stream>>>(idx, x, n, ws, stage);

    int mblk = (n + L_EXP * (SEGPAD - 1) + SEGPAD - 1) / SEGPAD;
    k_mlp<<<mblk, BLK, 0, stream>>>(ws, stage, W0, b0, W1, b1, W2, b2, out);
}

// Round 9
// 118.905 us; speedup vs baseline: 6.0979x; 1.0171x over previous
//
#include <hip/hip_runtime.h>

// Per-point expert-indexed MLP: h = LeakyReLU(h @ W[idx] + b[idx]) x3.
//
// Pipeline (4 dispatches):
//   k_hist    : 1024 pts/block histogram (int4 idx loads), partials [e][b]
//   k_scan    : 1 block x 1024; wave e scans expert e's <=512 partials
//   k_scatter : deterministic pos = soff[e] + prefix[e][b] + LDS rank;
//               stages ONLY pid (4 B/point — R8 staged 32 B rows; x is LLC-
//               resident 14 MB, so mlp gathers it directly instead).
//   k_mlp     : expert-uniform blocks, weights in LDS (4.8 KB, broadcast),
//               MPT=4 points/thread. VERIFIED LDS model: ~290 ds_read_b128/
//               thread x 12 cyc -> ~11us (R7: MPT=2 = 23us, R8: MPT=4 = ~11us).
//
// SPILL CONTAINMENT (R6): layer 0 fenced in halves, fused L1+L2 is a real
// loop (#pragma unroll 1), launch_bounds(256,2). Do not unroll that loop.

#define L_EXP 16
#define IN0   7
#define C0    16
#define C1    32
#define C2    16
#define NEG   0.2f
#define BLK   256
#define MPT   4
#define SEGPAD (BLK * MPT)   // 1024
#define CHUNK  1024          // points per hist/scatter block
#define NBM    512           // max hist/scatter blocks (n <= 524288)

// ws layout (int32):
//   [0..15]           counts per expert   (k_scan)
//   [16..32]          padded seg offsets, [32] = padded total (k_scan)
//   [64 .. 64+16*NBM) partial hist -> exclusive block prefixes, expert-major
//   [16384 .. )       perm: pid per sorted slot (pad slots keep 0xAA poison;
//                     k_mlp clamps inactive pids to 0)
#define WS_PART  64
#define WS_PERM  16384

__global__ void k_hist(const int* __restrict__ idx, int n, int* __restrict__ ws) {
    __shared__ int bins[L_EXP];
    int t = threadIdx.x;
    if (t < L_EXP) bins[t] = 0;
    __syncthreads();
    int i4 = blockIdx.x * CHUNK + t * 4;
    if (i4 + 3 < n) {
        int4 v = *reinterpret_cast<const int4*>(idx + i4);
        atomicAdd(&bins[v.x & 15], 1);
        atomicAdd(&bins[v.y & 15], 1);
        atomicAdd(&bins[v.z & 15], 1);
        atomicAdd(&bins[v.w & 15], 1);
    } else {
#pragma unroll
        for (int q = 0; q < 4; ++q)
            if (i4 + q < n) atomicAdd(&bins[idx[i4 + q] & 15], 1);
    }
    __syncthreads();
    if (t < L_EXP) ws[WS_PART + t * NBM + blockIdx.x] = bins[t];
}

__global__ void k_scan(int* __restrict__ ws, int nblk) {
    int t = threadIdx.x;          // 1024 threads = 16 waves, wave e = expert e
    int e = t >> 6, l = t & 63;
    int running = 0;
    for (int c = 0; c < nblk; c += 64) {
        int b = c + l;
        int v = (b < nblk) ? ws[WS_PART + e * NBM + b] : 0;
        int s = v;                 // inclusive wave scan
#pragma unroll
        for (int d = 1; d < 64; d <<= 1) {
            int u = __shfl_up(s, d, 64);
            if (l >= d) s += u;
        }
        if (b < nblk) ws[WS_PART + e * NBM + b] = running + (s - v);  // exclusive
        running += __shfl(s, 63, 64);
    }
    if (l == 0) ws[e] = running;   // expert total
    __syncthreads();
    if (t == 0) {
        int run = 0;
        for (int q = 0; q < L_EXP; ++q) {
            ws[16 + q] = run;
            run += ((ws[q] + SEGPAD - 1) / SEGPAD) * SEGPAD;
        }
        ws[32] = run;
    }
}

__global__ void k_scatter(const int* __restrict__ idx, int n,
                          int* __restrict__ ws) {
    __shared__ int soff[L_EXP];   // seg offset + block prefix, combined
    __shared__ int lcount[L_EXP];
    int t = threadIdx.x;
    if (t < L_EXP) {
        soff[t] = ws[16 + t] + ws[WS_PART + t * NBM + blockIdx.x];
        lcount[t] = 0;
    }
    __syncthreads();
    int i4 = blockIdx.x * CHUNK + t * 4;
#pragma unroll
    for (int q = 0; q < 4; ++q) {
        int i = i4 + q;
        if (i < n) {
            int e = idx[i] & 15;
            int r = atomicAdd(&lcount[e], 1);   // LDS only
            ws[WS_PERM + soff[e] + r] = i;
        }
    }
}

__device__ __forceinline__ float leaky(float a) { return fmaxf(a, NEG * a); }

__device__ __forceinline__ float4 f4_fma(float s, float4 w, float4 a) {
    a.x = fmaf(s, w.x, a.x);
    a.y = fmaf(s, w.y, a.y);
    a.z = fmaf(s, w.z, a.z);
    a.w = fmaf(s, w.w, a.w);
    return a;
}

__global__ void __launch_bounds__(BLK, 2) k_mlp(
    const int* __restrict__ meta, const float* __restrict__ x,
    const float* __restrict__ W0, const float* __restrict__ b0,
    const float* __restrict__ W1, const float* __restrict__ b1,
    const float* __restrict__ W2, const float* __restrict__ b2,
    float* __restrict__ out) {
    __shared__ __align__(16) float sW0[IN0 * C0];
    __shared__ __align__(16) float sB0[C0];
    __shared__ __align__(16) float sW1[C0 * C1];
    __shared__ __align__(16) float sB1[C1];
    __shared__ __align__(16) float sW2[C1 * C2];
    __shared__ __align__(16) float sB2[C2];

    int start = blockIdx.x * SEGPAD;
    if (start >= meta[32]) return;  // uniform

    int e = 0;
    while (start >= meta[16 + e + 1]) ++e;
    e = __builtin_amdgcn_readfirstlane(e);

    int t = threadIdx.x;
    {
        const float* w0p = W0 + e * (IN0 * C0);
        const float* w1p = W1 + e * (C0 * C1);
        const float* w2p = W2 + e * (C1 * C2);
        if (t < IN0 * C0) sW0[t] = w0p[t];
        if (t >= 128 && t < 128 + C0) sB0[t - 128] = b0[e * C0 + (t - 128)];
        if (t >= 160 && t < 160 + C1) sB1[t - 160] = b1[e * C1 + (t - 160)];
        if (t >= 192 && t < 192 + C2) sB2[t - 192] = b2[e * C2 + (t - 192)];
        for (int k = t; k < C0 * C1; k += BLK) sW1[k] = w1p[k];
        for (int k = t; k < C1 * C2; k += BLK) sW2[k] = w2p[k];
    }
    __syncthreads();

    int seg = meta[16 + e];
    int cnt = meta[e];
    int j0 = start - seg + t;

    float xv[MPT][IN0];
    int   pid[MPT];
    bool  act[MPT];
#pragma unroll
    for (int m = 0; m < MPT; ++m) {
        int j = j0 + m * BLK;
        act[m] = (j < cnt);
        int p = meta[WS_PERM + seg + j];   // pad slots hold poison ->
        pid[m] = act[m] ? p : 0;           // clamp (no divergent flow)
        const float* xp = x + (size_t)pid[m] * IN0;
        // two overlapping dwordx4: x[0..3], x[3..6] (rows are 4B-aligned)
        float4 a = *reinterpret_cast<const float4*>(xp);
        float4 b = *reinterpret_cast<const float4*>(xp + 3);
        xv[m][0] = a.x; xv[m][1] = a.y; xv[m][2] = a.z; xv[m][3] = a.w;
        xv[m][4] = b.y; xv[m][5] = b.z; xv[m][6] = b.w;
    }
    __builtin_amdgcn_sched_barrier(0);

    // ---- Layer 0: 7 -> 16, fenced halves (<=16 b128 in flight each) ----
    float h0[MPT][C0];
#pragma unroll
    for (int og = 0; og < C0 / 4; ++og) {
        float4 bb = *reinterpret_cast<const float4*>(&sB0[og * 4]);
        float4 acc[MPT];
#pragma unroll
        for (int m = 0; m < MPT; ++m) acc[m] = bb;
#pragma unroll
        for (int c = 0; c < IN0; ++c) {
            float4 w = *reinterpret_cast<const float4*>(&sW0[c * C0 + og * 4]);
#pragma unroll
            for (int m = 0; m < MPT; ++m) acc[m] = f4_fma(xv[m][c], w, acc[m]);
        }
#pragma unroll
        for (int m = 0; m < MPT; ++m) {
            h0[m][og * 4 + 0] = leaky(acc[m].x);
            h0[m][og * 4 + 1] = leaky(acc[m].y);
            h0[m][og * 4 + 2] = leaky(acc[m].z);
            h0[m][og * 4 + 3] = leaky(acc[m].w);
        }
        if (og == 1) __builtin_amdgcn_sched_barrier(0);  // mid-layer fence
    }
    __builtin_amdgcn_sched_barrier(0);

    // ---- Layers 1+2 fused; REAL loop (unroll 1) bounds in-flight loads ----
    float4 h2[MPT][C2 / 4];
#pragma unroll
    for (int og = 0; og < C2 / 4; ++og) {
        float4 bb = *reinterpret_cast<const float4*>(&sB2[og * 4]);
#pragma unroll
        for (int m = 0; m < MPT; ++m) h2[m][og] = bb;
    }
#pragma unroll 1
    for (int ch = 0; ch < C1 / 4; ++ch) {   // h1 neurons ch*4 .. ch*4+3
        float4 tv[MPT];
        float4 bb = *reinterpret_cast<const float4*>(&sB1[ch * 4]);
#pragma unroll
        for (int m = 0; m < MPT; ++m) tv[m] = bb;
#pragma unroll
        for (int c = 0; c < C0; ++c) {
            float4 w = *reinterpret_cast<const float4*>(&sW1[c * C1 + ch * 4]);
#pragma unroll
            for (int m = 0; m < MPT; ++m) tv[m] = f4_fma(h0[m][c], w, tv[m]);
        }
#pragma unroll
        for (int m = 0; m < MPT; ++m) {
            tv[m].x = leaky(tv[m].x); tv[m].y = leaky(tv[m].y);
            tv[m].z = leaky(tv[m].z); tv[m].w = leaky(tv[m].w);
        }
#pragma unroll
        for (int q = 0; q < 4; ++q) {
#pragma unroll
            for (int og = 0; og < C2 / 4; ++og) {
                float4 w = *reinterpret_cast<const float4*>(&sW2[(ch * 4 + q) * C2 + og * 4]);
#pragma unroll
                for (int m = 0; m < MPT; ++m) {
                    float s = (q == 0) ? tv[m].x : (q == 1) ? tv[m].y
                                       : (q == 2) ? tv[m].z : tv[m].w;
                    h2[m][og] = f4_fma(s, w, h2[m][og]);
                }
            }
        }
        __builtin_amdgcn_sched_barrier(0);  // fence at chunk boundary
    }

    // ---- predicated stores ----
#pragma unroll
    for (int m = 0; m < MPT; ++m) {
        if (act[m]) {
            float4* outp = reinterpret_cast<float4*>(out + (size_t)pid[m] * C2);
#pragma unroll
            for (int og = 0; og < C2 / 4; ++og) {
                float4 o = h2[m][og];
                o.x = leaky(o.x); o.y = leaky(o.y);
                o.z = leaky(o.z); o.w = leaky(o.w);
                outp[og] = o;
            }
        }
    }
}

extern "C" void kernel_launch(void* const* d_in, const int* in_sizes, int n_in,
                              void* d_out, int out_size, void* d_ws, size_t ws_size,
                              hipStream_t stream) {
    const float* x  = (const float*)d_in[0];
    const int*  idx = (const int*)d_in[1];
    const float* W0 = (const float*)d_in[2];
    const float* b0 = (const float*)d_in[3];
    const float* W1 = (const float*)d_in[4];
    const float* b1 = (const float*)d_in[5];
    const float* W2 = (const float*)d_in[6];
    const float* b2 = (const float*)d_in[7];
    float* out = (float*)d_out;

    int n = in_sizes[1];  // N
    int* ws = (int*)d_ws;

    int nblk = (n + CHUNK - 1) / CHUNK;   // <= NBM
    k_hist<<<nblk, BLK, 0, stream>>>(idx, n, ws);
    k_scan<<<1, 1024, 0, stream>>>(ws, nblk);
    k_scatter<<<nblk, BLK, 0, stream>>>(idx, n, ws);

    int mblk = (n + L_EXP * (SEGPAD - 1) + SEGPAD - 1) / SEGPAD;
    k_mlp<<<mblk, BLK, 0, stream>>>(ws, x, W0, b0, W1, b1, W2, b2, out);
}